// Round 3
// baseline (265.460 us; speedup 1.0000x reference)
//
#include <hip/hip_runtime.h>
#include <hip/hip_bf16.h>

#define NA 8400
#define BS 64
#define NC 80
#define TOPK 13
#define EPSF 1e-9f
#define SEG 2100          // NA / 4 waves
#define KMAX 33           // ceil(SEG/64)

// ---------------------------------------------------------------------------
// Kernel A: one block per batch, 4 waves. Wave w owns anchors
// [w*SEG, (w+1)*SEG). Each lane holds its <=33 align/overlap values in
// registers; 13 wave-synchronous argmax passes (no barriers) produce per-wave
// top-13 candidates; wave 0 merges 52 candidates, scatters v into norm[] via
// atomicMax (lanes 0..12 in parallel), and all threads write the mask row.
// ---------------------------------------------------------------------------
__global__ __launch_bounds__(256) void assign_kernel(
    const float* __restrict__ pd_scores,   // (BS, NC, NA)
    const float* __restrict__ pd_bboxes,   // (BS, 4, NA)
    const int*   __restrict__ gt_labels,   // (BS,)
    const float* __restrict__ gt_bboxes,   // (BS, 4)
    float*       __restrict__ out_mask,    // (BS, NA) = d_out + NA*BS
    float*       __restrict__ norm)        // (NA,) f32 ws, pre-zeroed
{
    __shared__ float s_cv[4 * TOPK];
    __shared__ int   s_ci[4 * TOPK];
    __shared__ float s_cov[4 * TOPK];
    __shared__ int   s_win[TOPK];
    __shared__ float s_mask;

    const int b = blockIdx.x;
    const int t = threadIdx.x;
    const int wave = t >> 6, lane = t & 63;
    const int seg_lo = wave * SEG;
    const int seg_hi = seg_lo + SEG;

    const float p1x = gt_bboxes[b * 4 + 0];
    const float p1y = gt_bboxes[b * 4 + 1];
    const float p2x = gt_bboxes[b * 4 + 2];
    const float p2y = gt_bboxes[b * 4 + 3];
    const float area1 = fmaxf(p2x - p1x, 0.f) * fmaxf(p2y - p1y, 0.f);
    const int lbl = gt_labels[b];
    const float* sc = pd_scores + (size_t)b * NC * NA + (size_t)lbl * NA;
    const float* bb = pd_bboxes + (size_t)b * 4 * NA;

    // ---- phase 0: align + overlap straight into registers (coalesced) ----
    float lv[KMAX], lov[KMAX];
    #pragma unroll
    for (int k = 0; k < KMAX; ++k) {
        int a = seg_lo + lane + (k << 6);
        bool ok = a < seg_hi;
        int aa = ok ? a : seg_lo;            // safe address for tail lanes
        float g1x = bb[0 * NA + aa];
        float g1y = bb[1 * NA + aa];
        float g2x = bb[2 * NA + aa];
        float g2y = bb[3 * NA + aa];
        float wx = fmaxf(fminf(p2x, g2x) - fmaxf(p1x, g1x), 0.f);
        float wy = fmaxf(fminf(p2y, g2y) - fmaxf(p1y, g1y), 0.f);
        float ovl = wx * wy;
        float area2 = fmaxf(g2x - g1x, 0.f) * fmaxf(g2y - g1y, 0.f);
        float o = ovl / (area1 + area2 - ovl + EPSF);
        float o2 = o * o;
        float score = sc[aa];
        lv[k]  = ok ? score * (o2 * o2 * o2) : -1.0f;   // align >= 0 if valid
        lov[k] = o;
    }

    // ---- phase 1: 13 wave-local argmax passes, zero barriers ----
    unsigned long long selmask = 0ULL;
    float cand_v = -2.f; int cand_i = 0x7fffffff; float cand_ov = 0.f;
    for (int j = 0; j < TOPK; ++j) {
        float mv = -2.f; int mk = 0; float mov = 0.f;
        #pragma unroll
        for (int k = 0; k < KMAX; ++k) {
            bool excl = (selmask >> k) & 1ULL;
            float v = excl ? -2.f : lv[k];
            if (v > mv) { mv = v; mk = k; mov = lov[k]; }
        }
        int mi = seg_lo + lane + (mk << 6);   // global anchor index (distinct/lane)
        float bv = mv; int bi = mi; float bov = mov;
        #pragma unroll
        for (int off = 1; off < 64; off <<= 1) {
            float ov_ = __shfl_xor(bv, off);
            int   oi_ = __shfl_xor(bi, off);
            float oo_ = __shfl_xor(bov, off);
            if (ov_ > bv || (ov_ == bv && oi_ < bi)) { bv = ov_; bi = oi_; bov = oo_; }
        }
        if (mi == bi) selmask |= 1ULL << mk;  // owner excludes its element
        if (lane == j) { cand_v = bv; cand_i = bi; cand_ov = bov; }
    }
    if (lane < TOPK) {
        s_cv [wave * TOPK + lane] = cand_v;
        s_ci [wave * TOPK + lane] = cand_i;
        s_cov[wave * TOPK + lane] = cand_ov;
    }
    __syncthreads();

    // ---- phase 2: wave 0 merges 52 candidates, scatters to norm[] ----
    if (wave == 0) {
        const int NC4 = 4 * TOPK;
        float v  = lane < NC4 ? s_cv[lane]  : -2.f;
        int   ci = lane < NC4 ? s_ci[lane]  : 0x7fffffff;
        float ov = lane < NC4 ? s_cov[lane] : 0.f;
        float pos_align = 0.f, pos_ov = 0.f;
        float wv_sel = 0.f; int wi_sel = 0;
        for (int j = 0; j < TOPK; ++j) {
            float bv = v; int bi = ci; float bov = ov;
            #pragma unroll
            for (int off = 1; off < 64; off <<= 1) {
                float ov_ = __shfl_xor(bv, off);
                int   oi_ = __shfl_xor(bi, off);
                float oo_ = __shfl_xor(bov, off);
                if (ov_ > bv || (ov_ == bv && oi_ < bi)) { bv = ov_; bi = oi_; bov = oo_; }
            }
            if (j == 0) pos_align = bv;          // top-1 = row max
            pos_ov = fmaxf(pos_ov, bov);
            if (lane == j) { wv_sel = bv; wi_sel = bi; }
            if (ci == bi) v = -2.f;              // exclude winner from my slot
        }
        float mask = pos_align > EPSF ? 1.f : 0.f;
        if (lane == 0) s_mask = mask;
        if (lane < TOPK) {
            s_win[lane] = wi_sel;
            if (mask != 0.f) {
                float vv = (wv_sel * pos_ov) / (pos_align + EPSF);  // same op order as ref
                atomicMax((int*)&norm[wi_sel], __float_as_int(vv)); // vv >= 0
            }
        }
    }
    __syncthreads();

    // ---- phase 3: mask row write (compare vs 13 winner indices) ----
    const float maskf = s_mask;
    int w0  = s_win[0],  w1  = s_win[1],  w2  = s_win[2],  w3 = s_win[3];
    int w4  = s_win[4],  w5  = s_win[5],  w6  = s_win[6],  w7 = s_win[7];
    int w8  = s_win[8],  w9  = s_win[9],  w10 = s_win[10], w11 = s_win[11];
    int w12 = s_win[12];
    float* om = out_mask + (size_t)b * NA;
    #pragma unroll
    for (int k = 0; k < KMAX; ++k) {
        int a = seg_lo + lane + (k << 6);
        if (a < seg_hi) {
            bool sel = (a == w0) | (a == w1) | (a == w2) | (a == w3) |
                       (a == w4) | (a == w5) | (a == w6) | (a == w7) |
                       (a == w8) | (a == w9) | (a == w10) | (a == w11) |
                       (a == w12);
            om[a] = (sel && maskf > 0.5f) ? 1.0f : 0.0f;
        }
    }
}

// ---------------------------------------------------------------------------
// Kernel B: out0[a*64 + b] = float(gt_labels[b]) * norm[a]   (shape (NA, BS))
// ---------------------------------------------------------------------------
__global__ __launch_bounds__(256) void scores_kernel(
    const float* __restrict__ norm,
    const int*   __restrict__ gt_labels,
    float*       __restrict__ out0)
{
    int idx = blockIdx.x * 256 + threadIdx.x;
    if (idx >= NA * BS) return;
    int b = idx & (BS - 1);
    int a = idx >> 6;
    out0[idx] = (float)gt_labels[b] * norm[a];
}

extern "C" void kernel_launch(void* const* d_in, const int* in_sizes, int n_in,
                              void* d_out, int out_size, void* d_ws, size_t ws_size,
                              hipStream_t stream) {
    const float* pd_scores = (const float*)d_in[0];
    const float* pd_bboxes = (const float*)d_in[1];
    const int*   gt_labels = (const int*)d_in[2];
    const float* gt_bboxes = (const float*)d_in[3];

    float* out0     = (float*)d_out;                  // (NA, BS)
    float* out_mask = out0 + (size_t)NA * BS;         // (BS, NA)
    float* norm     = (float*)d_ws;                   // (NA,)

    hipMemsetAsync(norm, 0, NA * sizeof(float), stream);
    assign_kernel<<<BS, 256, 0, stream>>>(pd_scores, pd_bboxes, gt_labels,
                                          gt_bboxes, out_mask, norm);
    scores_kernel<<<(NA * BS + 255) / 256, 256, 0, stream>>>(norm, gt_labels, out0);
}